// Round 4
// baseline (486.416 us; speedup 1.0000x reference)
//
#include <hip/hip_runtime.h>
#include <hip/hip_bf16.h>
#include <hip/hip_fp16.h>

#define TT 512
#define HIDD 2048
#define NH 16
#define NKV 8
#define DD 128
#define INTR 6144
#define SEQ 4096
#define SCALE 0.08838834764831845f

typedef __attribute__((ext_vector_type(8))) short short8;
typedef __attribute__((ext_vector_type(4))) float floatx4;

static __device__ __forceinline__ unsigned short f2b(float f) {
  unsigned int u = __float_as_uint(f);
  u += 0x7fffu + ((u >> 16) & 1u);
  return (unsigned short)(u >> 16);
}

static __device__ __forceinline__ unsigned int f2b2(float a, float b) {
  __hip_bfloat162 h = __float22bfloat162_rn(make_float2(a, b));
  return *reinterpret_cast<unsigned int*>(&h);
}

// ---------------- GEMM core v4: single-barrier 3-buffer DMA pipeline ----------
// C(BMx128) += A(BMx[kbeg:kend]) * B(128x[kbeg:kend])^T
// A bf16 staged [BM][32] (64B rows); B fp32 staged raw [128][32] with slot
// swizzle slot^=(row&7) on BOTH global source and frag read; B bf16 like A.
// Step t: vmcnt(NB) [tile t landed, t+1 in flight] -> s_barrier -> issue DMA
// tile t+2 into buf[(t+2)%3] (= buf read at t-1, retired by this barrier) ->
// frag reads buf[t%3] -> MFMA. ONE barrier/step, no lgkm drain, no reg staging.

static __device__ __forceinline__ void gld16(const void* g, void* l) {
  __builtin_amdgcn_global_load_lds(
      (const __attribute__((address_space(1))) unsigned int*)g,
      (__attribute__((address_space(3))) unsigned int*)l, 16, 0, 0);
}

template <int BM, bool B16>
static __device__ __forceinline__ void stage_tile(const unsigned short* __restrict__ A, int lda,
                                                  const void* __restrict__ B, int ldb, int k0,
                                                  unsigned char* buf, int wave, int lane) {
  {  // A tile: BM x 32 bf16, 64B rows. 1KB per (wave,issue) = 16 rows.
    const int rpw = BM >> 2;
    const int rl = lane >> 2;
    const int c8 = (lane & 3) << 3;
#pragma unroll
    for (int i = 0; i < BM / 64; ++i) {
      const int rbase = wave * rpw + i * 16;
      gld16(A + (size_t)(rbase + rl) * lda + k0 + c8, buf + (size_t)rbase * 64);
    }
  }
  unsigned char* Bb = buf + BM * 64;
  if constexpr (B16) {  // B tile: 128 x 32 bf16, like A
    const unsigned short* Bh = (const unsigned short*)B;
    const int rl = lane >> 2;
    const int c8 = (lane & 3) << 3;
#pragma unroll
    for (int i = 0; i < 2; ++i) {
      const int rbase = wave * 32 + i * 16;
      gld16(Bh + (size_t)(rbase + rl) * ldb + k0 + c8, Bb + (size_t)rbase * 64);
    }
  } else {  // B tile: 128 x 32 f32, 128B rows; storage slot sp holds logical slot sp^(r&7)
    const float* Bf = (const float*)B;
    const int rl = lane >> 3;
    const int sp = lane & 7;
#pragma unroll
    for (int i = 0; i < 4; ++i) {
      const int rbase = wave * 32 + i * 8;
      const int r = rbase + rl;
      gld16(Bf + (size_t)r * ldb + k0 + ((sp ^ (r & 7)) << 2), Bb + (size_t)rbase * 128);
    }
  }
}

template <int BM, bool B16>
static __device__ __forceinline__ void frags_from(const unsigned char* buf, int wr, int wc,
                                                  int lrow, int koff,
                                                  short8 (&af)[BM / 32], short8 (&bfr)[4]) {
  const unsigned short* Ab = (const unsigned short*)buf;
#pragma unroll
  for (int mi = 0; mi < BM / 32; ++mi)
    af[mi] = *reinterpret_cast<const short8*>(Ab + (size_t)(wr + mi * 16 + lrow) * 32 + koff);
  if constexpr (B16) {
    const unsigned short* Bb = (const unsigned short*)(buf + BM * 64);
#pragma unroll
    for (int ni = 0; ni < 4; ++ni)
      bfr[ni] = *reinterpret_cast<const short8*>(Bb + (size_t)(wc + ni * 16 + lrow) * 32 + koff);
  } else {
    const float* Bf = (const float*)(buf + BM * 64);
    const int s0 = koff >> 2;  // koff in {0,8,16,24} -> 16B slot 0,2,4,6
#pragma unroll
    for (int ni = 0; ni < 4; ++ni) {
      const int r = wc + ni * 16 + lrow;
      const float4 x = *reinterpret_cast<const float4*>(Bf + (size_t)r * 32 + ((s0 ^ (r & 7)) << 2));
      const float4 y = *reinterpret_cast<const float4*>(Bf + (size_t)r * 32 + (((s0 + 1) ^ (r & 7)) << 2));
      union { short8 s; unsigned int u[4]; } pk;
      pk.u[0] = f2b2(x.x, x.y); pk.u[1] = f2b2(x.z, x.w);
      pk.u[2] = f2b2(y.x, y.y); pk.u[3] = f2b2(y.z, y.w);
      bfr[ni] = pk.s;
    }
  }
}

template <int BM, bool B16>
static __device__ __forceinline__ void gemm_core(const unsigned short* __restrict__ A, int lda,
                                                 const void* __restrict__ B, int ldb,
                                                 int kbeg, int kend, floatx4 (&acc)[BM / 32][4],
                                                 unsigned char* Ls) {
  constexpr int MI = BM / 32;
  constexpr int TILE = BM * 64 + (B16 ? 8192 : 16384);
  constexpr int NB = (BM / 64) + (B16 ? 2 : 4);  // DMA insts per wave per tile
  const int tid = threadIdx.x;
  const int lane = tid & 63, wave = tid >> 6;
  const int wr = (wave >> 1) * (BM >> 1);
  const int wc = (wave & 1) << 6;
  const int lrow = lane & 15;
  const int koff = (lane >> 4) << 3;
  const int NT = (kend - kbeg) >> 5;  // all callers: NT >= 4
  unsigned char* P0 = Ls;
  unsigned char* P1 = Ls + TILE;
  unsigned char* P2 = Ls + 2 * TILE;
  stage_tile<BM, B16>(A, lda, B, ldb, kbeg,      P0, wave, lane);
  stage_tile<BM, B16>(A, lda, B, ldb, kbeg + 32, P1, wave, lane);
  for (int t = 0; t < NT; ++t) {
    if (t + 1 < NT) {  // tile t landed; tile t+1's NB loads stay in flight
      if constexpr (NB == 6)      asm volatile("s_waitcnt vmcnt(6)" ::: "memory");
      else if constexpr (NB == 4) asm volatile("s_waitcnt vmcnt(4)" ::: "memory");
      else                        asm volatile("s_waitcnt vmcnt(3)" ::: "memory");
    } else {
      asm volatile("s_waitcnt vmcnt(0)" ::: "memory");
    }
    __builtin_amdgcn_s_barrier();
    __builtin_amdgcn_sched_barrier(0);  // nothing crosses the barrier point
    if (t + 2 < NT)
      stage_tile<BM, B16>(A, lda, B, ldb, kbeg + (t + 2) * 32, P2, wave, lane);
    short8 af[MI], bfr[4];
    frags_from<BM, B16>(P0, wr, wc, lrow, koff, af, bfr);
#pragma unroll
    for (int mi = 0; mi < MI; ++mi)
#pragma unroll
      for (int ni = 0; ni < 4; ++ni)
        acc[mi][ni] = __builtin_amdgcn_mfma_f32_16x16x32_bf16(af[mi], bfr[ni], acc[mi][ni], 0, 0, 0);
    unsigned char* tmp = P0; P0 = P1; P1 = P2; P2 = tmp;
  }
}

#define EPI_VARS \
  const int lane = threadIdx.x & 63; \
  const int wave = threadIdx.x >> 6; \
  const int wc = (wave & 1) << 6;    \
  const int lrow = lane & 15;        \
  const int quad = lane >> 4;

#define ZERO_ACC(MI_) \
  floatx4 acc[MI_][4]; \
  _Pragma("unroll") for (int mi = 0; mi < MI_; ++mi) \
  _Pragma("unroll") for (int ni = 0; ni < 4; ++ni) { floatx4 z = {0.f, 0.f, 0.f, 0.f}; acc[mi][ni] = z; }

// XCD swizzle: 4 mt-blocks of one (nt,split) group at b, b+8, b+16, b+24 -> same bid%8 -> same XCD
template <int S>
static __device__ __forceinline__ void swz(int b, int& mt, int& nt, int& s) {
  mt = (b >> 3) & 3;
  const int gid = ((b >> 5) << 3) | (b & 7);
  nt = gid / S;
  s = gid - nt * S;
}

// ---------------- kernels ----------------

__global__ __launch_bounds__(1024) void k_rms1(const float* __restrict__ conv,
                                               const float* __restrict__ w,
                                               float* __restrict__ xb,
                                               unsigned short* __restrict__ h1b) {
  const int t0 = blockIdx.x << 5;  // 16 blocks x 32 t
  const int tid = threadIdx.x;
  const int j = tid & 31;   // t-lane (phase1) / c-lane (phase2 out)
  const int g = tid >> 5;   // c-row 0..31
  __shared__ float part[32][32];
  __shared__ float tile[32][33];
  __shared__ float rs[32];
  float ss = 0.f;
  for (int c0 = 0; c0 < HIDD; c0 += 32) {
    const float v = conv[(size_t)(c0 + g) * TT + t0 + j];
    ss += v * v;
  }
  part[g][j] = ss;
  __syncthreads();
  if (g == 0) {
    float tot = 0.f;
#pragma unroll
    for (int q = 0; q < 32; ++q) tot += part[q][j];
    rs[j] = rsqrtf(tot * (1.0f / HIDD) + 1e-6f);
  }
  __syncthreads();
  for (int c0 = 0; c0 < HIDD; c0 += 32) {
    tile[g][j] = conv[(size_t)(c0 + g) * TT + t0 + j];
    __syncthreads();
    const float v = tile[j][g];  // j = c index, g = t index
    const float rv = rs[g];
    xb[(size_t)(t0 + g) * HIDD + c0 + j] = v;
    h1b[(size_t)(t0 + g) * HIDD + c0 + j] = f2b(v * rv * w[c0 + j]);
    __syncthreads();
  }
}

__global__ __launch_bounds__(256) void k_gemm_qkv(const unsigned short* __restrict__ h1b,
                                                  const float* __restrict__ wq,
                                                  const float* __restrict__ wk,
                                                  const float* __restrict__ wv,
                                                  float* __restrict__ Pq) {
  __shared__ __align__(16) unsigned char Ls[3 * (128 * 64 + 16384)];
  int mt, nt, s;
  swz<4>(blockIdx.x, mt, nt, s);  // NT=32, S=4 -> 512 blocks
  const int m0 = mt << 7, n0 = nt << 7;
  const float* Bp;
  if (n0 < 2048)      Bp = wq + (size_t)n0 * HIDD;
  else if (n0 < 3072) Bp = wk + (size_t)(n0 - 2048) * HIDD;
  else                Bp = wv + (size_t)(n0 - 3072) * HIDD;
  ZERO_ACC(4)
  gemm_core<128, false>(h1b + (size_t)m0 * HIDD, HIDD, Bp, HIDD, s * 512, s * 512 + 512, acc, Ls);
  EPI_VARS
  const int wr = (wave >> 1) << 6;
  float* out = Pq + (size_t)s * (TT * 4096);
#pragma unroll
  for (int mi = 0; mi < 4; ++mi)
#pragma unroll
    for (int ni = 0; ni < 4; ++ni)
#pragma unroll
      for (int rr = 0; rr < 4; ++rr) {
        const int row = m0 + wr + mi * 16 + quad * 4 + rr;
        const int col = n0 + wc + ni * 16 + lrow;
        out[(size_t)row * 4096 + col] = acc[mi][ni][rr];
      }
}

__global__ __launch_bounds__(128) void k_rope(const float* __restrict__ Pq,
                                              const float* __restrict__ cosb,
                                              const float* __restrict__ sinb,
                                              const float* __restrict__ qnw,
                                              const float* __restrict__ knw,
                                              unsigned short* __restrict__ qb,
                                              unsigned short* __restrict__ kb,
                                              unsigned short* __restrict__ vtb,
                                              float* __restrict__ kout,
                                              float* __restrict__ vout) {
  const int u = blockIdx.x;  // 0..15 q, 16..23 k, 24..31 v
  const int t = blockIdx.y;
  const int d = threadIdx.x;
  __shared__ float red[2];
  __shared__ float sh[DD];
  int slot;
  if (u < NH)            slot = u * DD + d;
  else if (u < NH + NKV) slot = 2048 + (u - NH) * DD + d;
  else                   slot = 3072 + (u - NH - NKV) * DD + d;
  const size_t idx = (size_t)t * 4096 + slot;
  float val = Pq[idx] + Pq[idx + TT * 4096] + Pq[idx + 2 * TT * 4096] + Pq[idx + 3 * TT * 4096];
  if (u < NH + NKV) {
    float ss = val * val;
    const int lane = d & 63, wid = d >> 6;
#pragma unroll
    for (int o = 32; o; o >>= 1) ss += __shfl_xor(ss, o);
    if (!lane) red[wid] = ss;
    __syncthreads();
    const float r = rsqrtf((red[0] + red[1]) * (1.0f / DD) + 1e-6f);
    const float w = (u < NH) ? qnw[d] : knw[d];
    const float nv = val * r * w;
    sh[d] = nv;
    __syncthreads();
    const float partner = sh[d ^ 64];
    const float rh = (d < 64) ? -partner : partner;
    const float o = nv * cosb[(size_t)t * DD + d] + rh * sinb[(size_t)t * DD + d];
    if (u < NH) {
      qb[(size_t)u * TT * DD + (size_t)t * DD + d] = f2b(o);
    } else {
      const int kh = u - NH;
      kout[(size_t)kh * SEQ * DD + (size_t)t * DD + d] = o;
      kb[(size_t)kh * TT * DD + (size_t)t * DD + d] = f2b(o);
    }
  } else {
    const int vh = u - NH - NKV;
    vout[(size_t)vh * SEQ * DD + (size_t)t * DD + d] = val;
    vtb[(size_t)vh * DD * TT + (size_t)d * TT + t] = f2b(val);
  }
}

__global__ __launch_bounds__(256) void k_tail(const float* __restrict__ kc,
                                              const float* __restrict__ vc,
                                              float* __restrict__ ko,
                                              float* __restrict__ vo) {
  const int i = blockIdx.x * 256 + threadIdx.x;  // float4 index
  const int e = i << 2;
  const int s = (e >> 7) & (SEQ - 1);
  if (s >= TT) {
    reinterpret_cast<float4*>(ko)[i] = reinterpret_cast<const float4*>(kc)[i];
    reinterpret_cast<float4*>(vo)[i] = reinterpret_cast<const float4*>(vc)[i];
  }
}

__global__ __launch_bounds__(256) void k_scores(const unsigned short* __restrict__ qb,
                                                const unsigned short* __restrict__ kb,
                                                float* __restrict__ sc) {
  __shared__ __align__(16) unsigned char Ls[3 * (64 * 64 + 8192)];
  const int m0 = blockIdx.x << 6, n0 = blockIdx.y << 7, h = blockIdx.z;
  ZERO_ACC(2)
  gemm_core<64, true>(qb + (size_t)h * TT * DD + (size_t)m0 * DD, DD,
                      kb + (size_t)(h >> 1) * TT * DD + (size_t)n0 * DD, DD, 0, DD, acc, Ls);
  EPI_VARS
  const int wr = (wave >> 1) << 5;
  float* out = sc + (size_t)h * TT * TT;
#pragma unroll
  for (int mi = 0; mi < 2; ++mi)
#pragma unroll
    for (int ni = 0; ni < 4; ++ni)
#pragma unroll
      for (int rr = 0; rr < 4; ++rr) {
        const int t = m0 + wr + mi * 16 + quad * 4 + rr;
        const int s = n0 + wc + ni * 16 + lrow;
        float v = acc[mi][ni][rr] * SCALE;
        if (s > t) v += -10000.0f;
        out[(size_t)t * TT + s] = v;
      }
}

__global__ __launch_bounds__(256) void k_softmax(const float* __restrict__ sc,
                                                 unsigned short* __restrict__ Pb) {
  const int h = blockIdx.x >> 9, t = blockIdx.x & 511;
  const int tid = threadIdx.x;
  const float* row = sc + ((size_t)h * TT + t) * TT;
  float v0 = row[tid], v1 = row[tid + 256];
  __shared__ float red[4];
  const int lane = tid & 63, wid = tid >> 6;
  float m = fmaxf(v0, v1);
#pragma unroll
  for (int o = 32; o; o >>= 1) m = fmaxf(m, __shfl_xor(m, o));
  if (!lane) red[wid] = m;
  __syncthreads();
  m = fmaxf(fmaxf(red[0], red[1]), fmaxf(red[2], red[3]));
  const float e0 = __expf(v0 - m), e1 = __expf(v1 - m);
  float s = e0 + e1;
  __syncthreads();
#pragma unroll
  for (int o = 32; o; o >>= 1) s += __shfl_xor(s, o);
  if (!lane) red[wid] = s;
  __syncthreads();
  const float inv = 1.0f / (red[0] + red[1] + red[2] + red[3]);
  unsigned short* orow = Pb + ((size_t)h * TT + t) * TT;
  orow[tid] = f2b(e0 * inv);
  orow[tid + 256] = f2b(e1 * inv);
}

__global__ __launch_bounds__(256) void k_pv(const unsigned short* __restrict__ Pb,
                                            const unsigned short* __restrict__ vtb,
                                            float* __restrict__ Ppv) {
  __shared__ __align__(16) unsigned char Ls[3 * (64 * 64 + 8192)];
  const int m0 = blockIdx.x << 6, h = blockIdx.y, s = blockIdx.z;
  ZERO_ACC(2)
  gemm_core<64, true>(Pb + (size_t)h * TT * TT + (size_t)m0 * TT, TT,
                      vtb + (size_t)(h >> 1) * DD * TT, TT, s * 128, s * 128 + 128, acc, Ls);
  EPI_VARS
  const int wr = (wave >> 1) << 5;
  float* out = Ppv + (size_t)s * (TT * HIDD);
#pragma unroll
  for (int mi = 0; mi < 2; ++mi)
#pragma unroll
    for (int ni = 0; ni < 4; ++ni)
#pragma unroll
      for (int rr = 0; rr < 4; ++rr) {
        const int row = m0 + wr + mi * 16 + quad * 4 + rr;
        const int col = wc + ni * 16 + lrow;
        out[(size_t)row * HIDD + h * DD + col] = acc[mi][ni][rr];
      }
}

__global__ __launch_bounds__(256) void k_red_pv(const float* __restrict__ Ppv,
                                                unsigned short* __restrict__ o_inb) {
  const int i = blockIdx.x * 256 + threadIdx.x;  // float4 index over 512*2048/4
  const float4* p = reinterpret_cast<const float4*>(Ppv);
  float4 a = p[i];
  const float4 b = p[i + 262144], c = p[i + 524288], d = p[i + 786432];
  a.x += b.x + c.x + d.x; a.y += b.y + c.y + d.y;
  a.z += b.z + c.z + d.z; a.w += b.w + c.w + d.w;
  uint2 o;
  o.x = f2b2(a.x, a.y);
  o.y = f2b2(a.z, a.w);
  *reinterpret_cast<uint2*>(o_inb + (size_t)i * 4) = o;
}

__global__ __launch_bounds__(256) void k_gemm_o(const unsigned short* __restrict__ o_inb,
                                                const float* __restrict__ wo,
                                                float* __restrict__ Po) {
  __shared__ __align__(16) unsigned char Ls[3 * (128 * 64 + 16384)];
  int mt, nt, s;
  swz<8>(blockIdx.x, mt, nt, s);  // NT=16, S=8 -> 512 blocks
  const int m0 = mt << 7, n0 = nt << 7;
  ZERO_ACC(4)
  gemm_core<128, false>(o_inb + (size_t)m0 * HIDD, HIDD, wo + (size_t)n0 * HIDD, HIDD,
                        s * 256, s * 256 + 256, acc, Ls);
  EPI_VARS
  const int wr = (wave >> 1) << 6;
  float* out = Po + (size_t)s * (TT * HIDD);
#pragma unroll
  for (int mi = 0; mi < 4; ++mi)
#pragma unroll
    for (int ni = 0; ni < 4; ++ni)
#pragma unroll
      for (int rr = 0; rr < 4; ++rr) {
        const int row = m0 + wr + mi * 16 + quad * 4 + rr;
        const int col = n0 + wc + ni * 16 + lrow;
        out[(size_t)row * HIDD + col] = acc[mi][ni][rr];
      }
}

__global__ __launch_bounds__(256) void k_rms2(const float* __restrict__ xb,
                                              const float* __restrict__ Po,
                                              const float* __restrict__ w,
                                              float* __restrict__ hidden,
                                              unsigned short* __restrict__ h2b) {
  const int t = blockIdx.x;
  const int tid = threadIdx.x;
  float2 v[4];
  float ss = 0.f;
#pragma unroll
  for (int i = 0; i < 4; ++i) {
    const int c = (tid << 1) + (i << 9);
    const size_t idx = (size_t)t * HIDD + c;
    float2 a = *reinterpret_cast<const float2*>(xb + idx);
#pragma unroll
    for (int sp = 0; sp < 8; ++sp) {
      const float2 b = *reinterpret_cast<const float2*>(Po + idx + (size_t)sp * (TT * HIDD));
      a.x += b.x; a.y += b.y;
    }
    v[i] = a;
    ss += a.x * a.x + a.y * a.y;
  }
  __shared__ float red[4];
  const int lane = tid & 63, wid = tid >> 6;
#pragma unroll
  for (int o = 32; o; o >>= 1) ss += __shfl_xor(ss, o);
  if (!lane) red[wid] = ss;
  __syncthreads();
  const float tot = red[0] + red[1] + red[2] + red[3];
  const float r = rsqrtf(tot * (1.0f / HIDD) + 1e-6f);
#pragma unroll
  for (int i = 0; i < 4; ++i) {
    const int c = (tid << 1) + (i << 9);
    const size_t idx = (size_t)t * HIDD + c;
    *reinterpret_cast<float2*>(hidden + idx) = v[i];
    const float2 wv2 = *reinterpret_cast<const float2*>(w + c);
    *reinterpret_cast<unsigned int*>(h2b + idx) = f2b2(v[i].x * r * wv2.x, v[i].y * r * wv2.y);
  }
}

// gate_up GEMM: BM=128, split-K=2, fp16 partials.
// grid 768 = 4 mt x 96 nt x 2 s; LDS 73728 -> 2 blocks/CU.
__global__ __launch_bounds__(256) void k_gemm_gu(const unsigned short* __restrict__ h2b,
                                                 const float* __restrict__ wgu,
                                                 __half* __restrict__ guh) {
  __shared__ __align__(16) unsigned char Ls[3 * (128 * 64 + 16384)];
  int mt, nt, s;
  swz<2>(blockIdx.x, mt, nt, s);  // NT=96, S=2 -> 768 blocks
  const int m0 = mt << 7, n0 = nt << 7;
  ZERO_ACC(4)
  gemm_core<128, false>(h2b + (size_t)m0 * HIDD, HIDD, wgu + (size_t)n0 * HIDD, HIDD,
                        s * 1024, s * 1024 + 1024, acc, Ls);
  EPI_VARS
  const int wr = (wave >> 1) << 6;
  __half* out = guh + (size_t)s * (TT * 2 * INTR);
#pragma unroll
  for (int mi = 0; mi < 4; ++mi)
#pragma unroll
    for (int ni = 0; ni < 4; ++ni)
#pragma unroll
      for (int rr = 0; rr < 4; ++rr) {
        const int row = m0 + wr + mi * 16 + quad * 4 + rr;
        const int col = n0 + wc + ni * 16 + lrow;
        out[(size_t)row * (2 * INTR) + col] = __float2half(acc[mi][ni][rr]);
      }
}

__global__ __launch_bounds__(256) void k_silu(const __half* __restrict__ guh,
                                              unsigned short* __restrict__ actb) {
  const int j0 = (blockIdx.x * 256 + threadIdx.x) << 1;  // grid.x = 12
  const int t = blockIdx.y;
  const size_t base = (size_t)t * (2 * INTR) + j0;
  const size_t off = (size_t)TT * (2 * INTR);
  const float2 g0 = __half22float2(*reinterpret_cast<const __half2*>(guh + base));
  const float2 g1 = __half22float2(*reinterpret_cast<const __half2*>(guh + off + base));
  const float2 u0 = __half22float2(*reinterpret_cast<const __half2*>(guh + base + INTR));
  const float2 u1 = __half22float2(*reinterpret_cast<const __half2*>(guh + off + base + INTR));
  const float gx = g0.x + g1.x, gy = g0.y + g1.y;
  const float ux = u0.x + u1.x, uy = u0.y + u1.y;
  const float a0 = gx / (1.f + __expf(-gx)) * ux;
  const float a1 = gy / (1.f + __expf(-gy)) * uy;
  *reinterpret_cast<unsigned int*>(actb + (size_t)t * INTR + j0) = f2b2(a0, a1);
}

__global__ __launch_bounds__(256) void k_gemm_down(const unsigned short* __restrict__ actb,
                                                   const float* __restrict__ wdn,
                                                   float* __restrict__ Pdn) {
  __shared__ __align__(16) unsigned char Ls[3 * (128 * 64 + 16384)];
  int mt, nt, s;
  swz<8>(blockIdx.x, mt, nt, s);  // NT=16, S=8 -> 512 blocks
  const int m0 = mt << 7, n0 = nt << 7;
  ZERO_ACC(4)
  gemm_core<128, false>(actb + (size_t)m0 * INTR, INTR, wdn + (size_t)n0 * INTR, INTR,
                        s * 768, s * 768 + 768, acc, Ls);
  EPI_VARS
  const int wr = (wave >> 1) << 6;
  float* out = Pdn + (size_t)s * (TT * HIDD);
#pragma unroll
  for (int mi = 0; mi < 4; ++mi)
#pragma unroll
    for (int ni = 0; ni < 4; ++ni)
#pragma unroll
      for (int rr = 0; rr < 4; ++rr) {
        const int row = m0 + wr + mi * 16 + quad * 4 + rr;
        const int col = n0 + wc + ni * 16 + lrow;
        out[(size_t)row * HIDD + col] = acc[mi][ni][rr];
      }
}

__global__ __launch_bounds__(256) void k_final(const float* __restrict__ hidden,
                                               const float* __restrict__ Pdn,
                                               float* __restrict__ out0) {
  __shared__ float tile[32][33];
  const int c0 = blockIdx.x << 5, t0 = blockIdx.y << 5;
  const int tx = threadIdx.x & 31, ty0 = (threadIdx.x >> 5) << 2;
#pragma unroll
  for (int i = 0; i < 4; ++i) {
    const int t = t0 + ty0 + i;
    const size_t idx = (size_t)t * HIDD + c0 + tx;
    float a = hidden[idx];
#pragma unroll
    for (int sp = 0; sp < 8; ++sp) a += Pdn[idx + (size_t)sp * (TT * HIDD)];
    tile[ty0 + i][tx] = a;
  }
  __syncthreads();
#pragma unroll
  for (int i = 0; i < 4; ++i)
    out0[(size_t)(c0 + ty0 + i) * TT + t0 + tx] = tile[tx][ty0 + i];
}

extern "C" void kernel_launch(void* const* d_in, const int* in_sizes, int n_in,
                              void* d_out, int out_size, void* d_ws, size_t ws_size,
                              hipStream_t stream) {
  const float* conv   = (const float*)d_in[0];
  const float* cosb   = (const float*)d_in[1];
  const float* sinb   = (const float*)d_in[2];
  const float* kcache = (const float*)d_in[5];
  const float* vcache = (const float*)d_in[6];
  const float* wq  = (const float*)d_in[7];
  const float* wk  = (const float*)d_in[8];
  const float* wv  = (const float*)d_in[9];
  const float* wo  = (const float*)d_in[10];
  const float* ln1 = (const float*)d_in[11];
  const float* ln2 = (const float*)d_in[12];
  const float* qnw = (const float*)d_in[13];
  const float* knw = (const float*)d_in[14];
  const float* wgu = (const float*)d_in[15];
  const float* wdn = (const float*)d_in[16];

  float* ws = (float*)d_ws;
  // layout (floats): total 14,155,776 f = 56.6 MB (< 71.3 MB proven in R1/R2)
  float* xb = ws + 0;                                      // 1,048,576
  unsigned short* h1b  = (unsigned short*)(ws + 1048576);  // 524,288 f ; later o_inb
  unsigned short* o_inb = h1b;
  unsigned short* h2b  = (unsigned short*)(ws + 1572864);  // 524,288 f
  float* hidden = ws + 2097152;                            // 1,048,576
  unsigned short* qb  = (unsigned short*)(ws + 3145728);   // 16*512*128 us
  unsigned short* kb  = qb + 1048576;                      // 8*512*128 us
  unsigned short* vtb = kb + 524288;                       // 8*128*512 us (d-major)
  unsigned short* actb = (unsigned short*)(ws + 4194304);  // 512*6144 us = 1,572,864 f
  float* R   = ws + 5767168;                               // 8,388,608 f shared region:
  float* Pq  = R;                                          //  qkv:   4 x 2,097,152
  unsigned short* Pb = (unsigned short*)R;                 //  attn:  2,097,152 f-slots
  float* sc  = R + 2097152;                                //  attn:  4,194,304
  float* Ppv = R + 2097152;                                //  pv:    4 x 1,048,576 (over dead sc)
  float* Po  = R;                                          //  o:     8 x 1,048,576
  __half* guh = (__half*)R;                                //  mlp:   2 x 6,291,456 halves = 6,291,456 f
  float* Pdn = R;                                          //  down:  8 x 1,048,576

  float* out0 = (float*)d_out;   // (HID, T)
  float* kout = out0 + 1048576;  // (NKV, SEQ, D)
  float* vout = kout + 4194304;  // (NKV, SEQ, D)

  k_rms1<<<16, 1024, 0, stream>>>(conv, ln1, xb, h1b);
  k_gemm_qkv<<<512, 256, 0, stream>>>(h1b, wq, wk, wv, Pq);
  k_rope<<<dim3(NH + 2 * NKV, TT), 128, 0, stream>>>(Pq, cosb, sinb, qnw, knw, qb, kb, vtb, kout, vout);
  k_tail<<<4096, 256, 0, stream>>>(kcache, vcache, kout, vout);
  k_scores<<<dim3(8, 4, NH), 256, 0, stream>>>(qb, kb, sc);
  k_softmax<<<NH * TT, 256, 0, stream>>>(sc, Pb);
  k_pv<<<dim3(8, NH, 4), 256, 0, stream>>>(Pb, vtb, Ppv);
  k_red_pv<<<1024, 256, 0, stream>>>(Ppv, o_inb);
  k_gemm_o<<<512, 256, 0, stream>>>(o_inb, wo, Po);
  k_rms2<<<TT, 256, 0, stream>>>(xb, Po, ln2, hidden, h2b);
  k_gemm_gu<<<768, 256, 0, stream>>>(h2b, wgu, guh);
  k_silu<<<dim3(12, TT), 256, 0, stream>>>(guh, actb);
  k_gemm_down<<<512, 256, 0, stream>>>(actb, wdn, Pdn);
  k_final<<<dim3(HIDD / 32, TT / 32), 256, 0, stream>>>(hidden, Pdn, out0);
}

// Round 5
// 470.681 us; speedup vs baseline: 1.0334x; 1.0334x over previous
//
#include <hip/hip_runtime.h>
#include <hip/hip_bf16.h>
#include <hip/hip_fp16.h>

#define TT 512
#define HIDD 2048
#define NH 16
#define NKV 8
#define DD 128
#define INTR 6144
#define SEQ 4096
#define SCALE 0.08838834764831845f

typedef __attribute__((ext_vector_type(8))) short short8;
typedef __attribute__((ext_vector_type(4))) float floatx4;

static __device__ __forceinline__ unsigned short f2b(float f) {
  unsigned int u = __float_as_uint(f);
  u += 0x7fffu + ((u >> 16) & 1u);
  return (unsigned short)(u >> 16);
}

static __device__ __forceinline__ unsigned int f2b2(float a, float b) {
  __hip_bfloat162 h = __float22bfloat162_rn(make_float2(a, b));
  return *reinterpret_cast<unsigned int*>(&h);
}

// ---------------- GEMM core (R3 structure + frag-read bank-conflict swizzle) ----
// C(BMx128) += A(BMx[kbeg:kend]) * B(128x[kbeg:kend])^T
// A bf16 staged [BM][32] (64B rows). Unswizzled, the 16-row ds_read_b128 frag
// pattern is an 8-way bank conflict (64B rows alias every 2 rows). Fix: 16B-slot
// XOR swizzle q' = q ^ ((row>>1)&3), applied on the per-lane GLOBAL source
// (LDS dest stays linear for global_load_lds) AND on the frag read -> 2-way (free).
// bf16-B same. fp32-B keeps its slot^(row&7) swizzle (already conflict-free).
// Pipeline: 2 LDS buffers, 2-deep DMA, counted vmcnt, raw barriers (best measured).

static __device__ __forceinline__ void gld16(const void* g, void* l) {
  __builtin_amdgcn_global_load_lds(
      (const __attribute__((address_space(1))) unsigned int*)g,
      (__attribute__((address_space(3))) unsigned int*)l, 16, 0, 0);
}

template <int BM, bool B16>
static __device__ __forceinline__ void stage_tile(const unsigned short* __restrict__ A, int lda,
                                                  const void* __restrict__ B, int ldb, int k0,
                                                  unsigned char* buf, int wave, int lane) {
  {  // A tile: BM x 32 bf16, 64B rows; source column slot swizzled by (row>>1)&3
    const int rpw = BM >> 2;
    const int rl = lane >> 2;
    const int c8 = (((lane & 3) ^ ((rl >> 1) & 3)) << 3);
#pragma unroll
    for (int i = 0; i < BM / 64; ++i) {
      const int rbase = wave * rpw + i * 16;  // multiple of 16 -> swizzle row-phase preserved
      gld16(A + (size_t)(rbase + rl) * lda + k0 + c8, buf + (size_t)rbase * 64);
    }
  }
  unsigned char* Bb = buf + BM * 64;
  if constexpr (B16) {  // B tile: 128 x 32 bf16, same swizzle as A
    const unsigned short* Bh = (const unsigned short*)B;
    const int rl = lane >> 2;
    const int c8 = (((lane & 3) ^ ((rl >> 1) & 3)) << 3);
#pragma unroll
    for (int i = 0; i < 2; ++i) {
      const int rbase = wave * 32 + i * 16;
      gld16(Bh + (size_t)(rbase + rl) * ldb + k0 + c8, Bb + (size_t)rbase * 64);
    }
  } else {  // B tile: 128 x 32 f32, 128B rows; storage slot sp holds logical slot sp^(r&7)
    const float* Bf = (const float*)B;
    const int rl = lane >> 3;
    const int sp = lane & 7;
#pragma unroll
    for (int i = 0; i < 4; ++i) {
      const int rbase = wave * 32 + i * 8;
      const int r = rbase + rl;
      gld16(Bf + (size_t)r * ldb + k0 + ((sp ^ (r & 7)) << 2), Bb + (size_t)rbase * 128);
    }
  }
}

template <int BM, bool B16>
static __device__ __forceinline__ void frags_from(const unsigned char* buf, int wr, int wc,
                                                  int lrow, int q,
                                                  short8 (&af)[BM / 32], short8 (&bfr)[4]) {
  const int koffA = ((q ^ ((lrow >> 1) & 3)) << 3);  // swizzled 8-elem slot
  const unsigned short* Ab = (const unsigned short*)buf;
#pragma unroll
  for (int mi = 0; mi < BM / 32; ++mi)
    af[mi] = *reinterpret_cast<const short8*>(Ab + (size_t)(wr + mi * 16 + lrow) * 32 + koffA);
  if constexpr (B16) {
    const unsigned short* Bb = (const unsigned short*)(buf + BM * 64);
#pragma unroll
    for (int ni = 0; ni < 4; ++ni)
      bfr[ni] = *reinterpret_cast<const short8*>(Bb + (size_t)(wc + ni * 16 + lrow) * 32 + koffA);
  } else {
    const float* Bf = (const float*)(buf + BM * 64);
    const int s0 = q << 1;  // 16B slot among 8 per fp32 row
#pragma unroll
    for (int ni = 0; ni < 4; ++ni) {
      const int r = wc + ni * 16 + lrow;
      const float4 x = *reinterpret_cast<const float4*>(Bf + (size_t)r * 32 + ((s0 ^ (r & 7)) << 2));
      const float4 y = *reinterpret_cast<const float4*>(Bf + (size_t)r * 32 + (((s0 + 1) ^ (r & 7)) << 2));
      union { short8 s; unsigned int u[4]; } pk;
      pk.u[0] = f2b2(x.x, x.y); pk.u[1] = f2b2(x.z, x.w);
      pk.u[2] = f2b2(y.x, y.y); pk.u[3] = f2b2(y.z, y.w);
      bfr[ni] = pk.s;
    }
  }
}

template <int BM, bool B16>
static __device__ __forceinline__ void gemm_core(const unsigned short* __restrict__ A, int lda,
                                                 const void* __restrict__ B, int ldb,
                                                 int kbeg, int kend, floatx4 (&acc)[BM / 32][4],
                                                 unsigned char* Ls) {
  constexpr int MI = BM / 32;
  constexpr int TILE = BM * 64 + (B16 ? 8192 : 16384);
  constexpr int NB = (BM / 64) + (B16 ? 2 : 4);  // DMA insts per wave per tile
  const int tid = threadIdx.x;
  const int lane = tid & 63, wave = tid >> 6;
  const int wr = (wave >> 1) * (BM >> 1);
  const int wc = (wave & 1) << 6;
  const int lrow = lane & 15;
  const int q = lane >> 4;
  const int NT = (kend - kbeg) >> 5;  // all callers: NT >= 4
  stage_tile<BM, B16>(A, lda, B, ldb, kbeg,      Ls,        wave, lane);
  stage_tile<BM, B16>(A, lda, B, ldb, kbeg + 32, Ls + TILE, wave, lane);
  int p = 0;
  for (int t = 0; t < NT - 1; ++t) {
    // wait tile t landed (tile t+1's NB loads stay in flight)
    if constexpr (NB == 6)      asm volatile("s_waitcnt vmcnt(6)" ::: "memory");
    else if constexpr (NB == 3) asm volatile("s_waitcnt vmcnt(3)" ::: "memory");
    else if constexpr (NB == 4) asm volatile("s_waitcnt vmcnt(4)" ::: "memory");
    else                        asm volatile("s_waitcnt vmcnt(5)" ::: "memory");
    __builtin_amdgcn_sched_barrier(0);
    __builtin_amdgcn_s_barrier();
    short8 af[MI], bfr[4];
    frags_from<BM, B16>(Ls + p * TILE, wr, wc, lrow, q, af, bfr);
    asm volatile("s_waitcnt lgkmcnt(0)" ::: "memory");
    __builtin_amdgcn_sched_barrier(0);
    __builtin_amdgcn_s_barrier();  // all waves' reads of buf p retired -> safe to re-DMA
    if (t + 2 < NT)
      stage_tile<BM, B16>(A, lda, B, ldb, kbeg + (t + 2) * 32, Ls + p * TILE, wave, lane);
#pragma unroll
    for (int mi = 0; mi < MI; ++mi)
#pragma unroll
      for (int ni = 0; ni < 4; ++ni)
        acc[mi][ni] = __builtin_amdgcn_mfma_f32_16x16x32_bf16(af[mi], bfr[ni], acc[mi][ni], 0, 0, 0);
    p ^= 1;
  }
  asm volatile("s_waitcnt vmcnt(0)" ::: "memory");
  __builtin_amdgcn_sched_barrier(0);
  __builtin_amdgcn_s_barrier();
  {
    short8 af[MI], bfr[4];
    frags_from<BM, B16>(Ls + p * TILE, wr, wc, lrow, q, af, bfr);
#pragma unroll
    for (int mi = 0; mi < MI; ++mi)
#pragma unroll
      for (int ni = 0; ni < 4; ++ni)
        acc[mi][ni] = __builtin_amdgcn_mfma_f32_16x16x32_bf16(af[mi], bfr[ni], acc[mi][ni], 0, 0, 0);
  }
}

#define EPI_VARS \
  const int lane = threadIdx.x & 63; \
  const int wave = threadIdx.x >> 6; \
  const int wc = (wave & 1) << 6;    \
  const int lrow = lane & 15;        \
  const int quad = lane >> 4;

#define ZERO_ACC(MI_) \
  floatx4 acc[MI_][4]; \
  _Pragma("unroll") for (int mi = 0; mi < MI_; ++mi) \
  _Pragma("unroll") for (int ni = 0; ni < 4; ++ni) { floatx4 z = {0.f, 0.f, 0.f, 0.f}; acc[mi][ni] = z; }

// XCD swizzle: 4 mt-blocks of one (nt,split) group at b, b+8, b+16, b+24 -> same bid%8 -> same XCD
template <int S>
static __device__ __forceinline__ void swz(int b, int& mt, int& nt, int& s) {
  mt = (b >> 3) & 3;
  const int gid = ((b >> 5) << 3) | (b & 7);
  nt = gid / S;
  s = gid - nt * S;
}

// ---------------- kernels ----------------

__global__ __launch_bounds__(1024) void k_rms1(const float* __restrict__ conv,
                                               const float* __restrict__ w,
                                               float* __restrict__ xb,
                                               unsigned short* __restrict__ h1b) {
  const int t0 = blockIdx.x << 5;  // 16 blocks x 32 t
  const int tid = threadIdx.x;
  const int j = tid & 31;   // t-lane (phase1) / c-lane (phase2 out)
  const int g = tid >> 5;   // c-row 0..31
  __shared__ float part[32][32];
  __shared__ float tile[32][33];
  __shared__ float rs[32];
  float ss = 0.f;
  for (int c0 = 0; c0 < HIDD; c0 += 32) {
    const float v = conv[(size_t)(c0 + g) * TT + t0 + j];
    ss += v * v;
  }
  part[g][j] = ss;
  __syncthreads();
  if (g == 0) {
    float tot = 0.f;
#pragma unroll
    for (int q = 0; q < 32; ++q) tot += part[q][j];
    rs[j] = rsqrtf(tot * (1.0f / HIDD) + 1e-6f);
  }
  __syncthreads();
  for (int c0 = 0; c0 < HIDD; c0 += 32) {
    tile[g][j] = conv[(size_t)(c0 + g) * TT + t0 + j];
    __syncthreads();
    const float v = tile[j][g];  // j = c index, g = t index
    const float rv = rs[g];
    xb[(size_t)(t0 + g) * HIDD + c0 + j] = v;
    h1b[(size_t)(t0 + g) * HIDD + c0 + j] = f2b(v * rv * w[c0 + j]);
    __syncthreads();
  }
}

__global__ __launch_bounds__(256) void k_gemm_qkv(const unsigned short* __restrict__ h1b,
                                                  const float* __restrict__ wq,
                                                  const float* __restrict__ wk,
                                                  const float* __restrict__ wv,
                                                  __half* __restrict__ Pq) {
  __shared__ __align__(16) unsigned char Ls[2 * (128 * 64 + 16384)];
  int mt, nt, s;
  swz<4>(blockIdx.x, mt, nt, s);  // NT=32, S=4 -> 512 blocks
  const int m0 = mt << 7, n0 = nt << 7;
  const float* Bp;
  if (n0 < 2048)      Bp = wq + (size_t)n0 * HIDD;
  else if (n0 < 3072) Bp = wk + (size_t)(n0 - 2048) * HIDD;
  else                Bp = wv + (size_t)(n0 - 3072) * HIDD;
  ZERO_ACC(4)
  gemm_core<128, false>(h1b + (size_t)m0 * HIDD, HIDD, Bp, HIDD, s * 512, s * 512 + 512, acc, Ls);
  EPI_VARS
  const int wr = (wave >> 1) << 6;
  __half* out = Pq + (size_t)s * (TT * 4096);
#pragma unroll
  for (int mi = 0; mi < 4; ++mi)
#pragma unroll
    for (int ni = 0; ni < 4; ++ni)
#pragma unroll
      for (int rr = 0; rr < 4; ++rr) {
        const int row = m0 + wr + mi * 16 + quad * 4 + rr;
        const int col = n0 + wc + ni * 16 + lrow;
        out[(size_t)row * 4096 + col] = __float2half(acc[mi][ni][rr]);
      }
}

__global__ __launch_bounds__(128) void k_rope(const __half* __restrict__ Pq,
                                              const float* __restrict__ cosb,
                                              const float* __restrict__ sinb,
                                              const float* __restrict__ qnw,
                                              const float* __restrict__ knw,
                                              unsigned short* __restrict__ qb,
                                              unsigned short* __restrict__ kb,
                                              unsigned short* __restrict__ vtb,
                                              float* __restrict__ kout,
                                              float* __restrict__ vout) {
  const int u = blockIdx.x;  // 0..15 q, 16..23 k, 24..31 v
  const int t = blockIdx.y;
  const int d = threadIdx.x;
  __shared__ float red[2];
  __shared__ float sh[DD];
  int slot;
  if (u < NH)            slot = u * DD + d;
  else if (u < NH + NKV) slot = 2048 + (u - NH) * DD + d;
  else                   slot = 3072 + (u - NH - NKV) * DD + d;
  const size_t idx = (size_t)t * 4096 + slot;
  float val = __half2float(Pq[idx]) + __half2float(Pq[idx + (size_t)TT * 4096]) +
              __half2float(Pq[idx + 2 * (size_t)TT * 4096]) + __half2float(Pq[idx + 3 * (size_t)TT * 4096]);
  if (u < NH + NKV) {
    float ss = val * val;
    const int lane = d & 63, wid = d >> 6;
#pragma unroll
    for (int o = 32; o; o >>= 1) ss += __shfl_xor(ss, o);
    if (!lane) red[wid] = ss;
    __syncthreads();
    const float r = rsqrtf((red[0] + red[1]) * (1.0f / DD) + 1e-6f);
    const float w = (u < NH) ? qnw[d] : knw[d];
    const float nv = val * r * w;
    sh[d] = nv;
    __syncthreads();
    const float partner = sh[d ^ 64];
    const float rh = (d < 64) ? -partner : partner;
    const float o = nv * cosb[(size_t)t * DD + d] + rh * sinb[(size_t)t * DD + d];
    if (u < NH) {
      qb[(size_t)u * TT * DD + (size_t)t * DD + d] = f2b(o);
    } else {
      const int kh = u - NH;
      kout[(size_t)kh * SEQ * DD + (size_t)t * DD + d] = o;
      kb[(size_t)kh * TT * DD + (size_t)t * DD + d] = f2b(o);
    }
  } else {
    const int vh = u - NH - NKV;
    vout[(size_t)vh * SEQ * DD + (size_t)t * DD + d] = val;
    vtb[(size_t)vh * DD * TT + (size_t)d * TT + t] = f2b(val);
  }
}

__global__ __launch_bounds__(256) void k_tail(const float* __restrict__ kc,
                                              const float* __restrict__ vc,
                                              float* __restrict__ ko,
                                              float* __restrict__ vo) {
  const int i = blockIdx.x * 256 + threadIdx.x;  // float4 index
  const int e = i << 2;
  const int s = (e >> 7) & (SEQ - 1);
  if (s >= TT) {
    reinterpret_cast<float4*>(ko)[i] = reinterpret_cast<const float4*>(kc)[i];
    reinterpret_cast<float4*>(vo)[i] = reinterpret_cast<const float4*>(vc)[i];
  }
}

__global__ __launch_bounds__(256) void k_scores(const unsigned short* __restrict__ qb,
                                                const unsigned short* __restrict__ kb,
                                                float* __restrict__ sc) {
  __shared__ __align__(16) unsigned char Ls[2 * (64 * 64 + 8192)];
  const int m0 = blockIdx.x << 6, n0 = blockIdx.y << 7, h = blockIdx.z;
  ZERO_ACC(2)
  gemm_core<64, true>(qb + (size_t)h * TT * DD + (size_t)m0 * DD, DD,
                      kb + (size_t)(h >> 1) * TT * DD + (size_t)n0 * DD, DD, 0, DD, acc, Ls);
  EPI_VARS
  const int wr = (wave >> 1) << 5;
  float* out = sc + (size_t)h * TT * TT;
#pragma unroll
  for (int mi = 0; mi < 2; ++mi)
#pragma unroll
    for (int ni = 0; ni < 4; ++ni)
#pragma unroll
      for (int rr = 0; rr < 4; ++rr) {
        const int t = m0 + wr + mi * 16 + quad * 4 + rr;
        const int s = n0 + wc + ni * 16 + lrow;
        float v = acc[mi][ni][rr] * SCALE;
        if (s > t) v += -10000.0f;
        out[(size_t)t * TT + s] = v;
      }
}

__global__ __launch_bounds__(256) void k_softmax(const float* __restrict__ sc,
                                                 unsigned short* __restrict__ Pb) {
  const int h = blockIdx.x >> 9, t = blockIdx.x & 511;
  const int tid = threadIdx.x;
  const float* row = sc + ((size_t)h * TT + t) * TT;
  float v0 = row[tid], v1 = row[tid + 256];
  __shared__ float red[4];
  const int lane = tid & 63, wid = tid >> 6;
  float m = fmaxf(v0, v1);
#pragma unroll
  for (int o = 32; o; o >>= 1) m = fmaxf(m, __shfl_xor(m, o));
  if (!lane) red[wid] = m;
  __syncthreads();
  m = fmaxf(fmaxf(red[0], red[1]), fmaxf(red[2], red[3]));
  const float e0 = __expf(v0 - m), e1 = __expf(v1 - m);
  float s = e0 + e1;
  __syncthreads();
#pragma unroll
  for (int o = 32; o; o >>= 1) s += __shfl_xor(s, o);
  if (!lane) red[wid] = s;
  __syncthreads();
  const float inv = 1.0f / (red[0] + red[1] + red[2] + red[3]);
  unsigned short* orow = Pb + ((size_t)h * TT + t) * TT;
  orow[tid] = f2b(e0 * inv);
  orow[tid + 256] = f2b(e1 * inv);
}

__global__ __launch_bounds__(256) void k_pv(const unsigned short* __restrict__ Pb,
                                            const unsigned short* __restrict__ vtb,
                                            float* __restrict__ Ppv) {
  __shared__ __align__(16) unsigned char Ls[2 * (64 * 64 + 8192)];
  const int m0 = blockIdx.x << 6, h = blockIdx.y, s = blockIdx.z;
  ZERO_ACC(2)
  gemm_core<64, true>(Pb + (size_t)h * TT * TT + (size_t)m0 * TT, TT,
                      vtb + (size_t)(h >> 1) * DD * TT, TT, s * 128, s * 128 + 128, acc, Ls);
  EPI_VARS
  const int wr = (wave >> 1) << 5;
  float* out = Ppv + (size_t)s * (TT * HIDD);
#pragma unroll
  for (int mi = 0; mi < 2; ++mi)
#pragma unroll
    for (int ni = 0; ni < 4; ++ni)
#pragma unroll
      for (int rr = 0; rr < 4; ++rr) {
        const int row = m0 + wr + mi * 16 + quad * 4 + rr;
        const int col = wc + ni * 16 + lrow;
        out[(size_t)row * HIDD + h * DD + col] = acc[mi][ni][rr];
      }
}

__global__ __launch_bounds__(256) void k_red_pv(const float* __restrict__ Ppv,
                                                unsigned short* __restrict__ o_inb) {
  const int i = blockIdx.x * 256 + threadIdx.x;  // float4 index over 512*2048/4
  const float4* p = reinterpret_cast<const float4*>(Ppv);
  float4 a = p[i];
  const float4 b = p[i + 262144], c = p[i + 524288], d = p[i + 786432];
  a.x += b.x + c.x + d.x; a.y += b.y + c.y + d.y;
  a.z += b.z + c.z + d.z; a.w += b.w + c.w + d.w;
  uint2 o;
  o.x = f2b2(a.x, a.y);
  o.y = f2b2(a.z, a.w);
  *reinterpret_cast<uint2*>(o_inb + (size_t)i * 4) = o;
}

__global__ __launch_bounds__(256) void k_gemm_o(const unsigned short* __restrict__ o_inb,
                                                const float* __restrict__ wo,
                                                __half* __restrict__ Po) {
  __shared__ __align__(16) unsigned char Ls[2 * (128 * 64 + 16384)];
  int mt, nt, s;
  swz<16>(blockIdx.x, mt, nt, s);  // NT=16, S=16 -> 1024 blocks, K=128 each
  const int m0 = mt << 7, n0 = nt << 7;
  ZERO_ACC(4)
  gemm_core<128, false>(o_inb + (size_t)m0 * HIDD, HIDD, wo + (size_t)n0 * HIDD, HIDD,
                        s * 128, s * 128 + 128, acc, Ls);
  EPI_VARS
  const int wr = (wave >> 1) << 6;
  __half* out = Po + (size_t)s * (TT * HIDD);
#pragma unroll
  for (int mi = 0; mi < 4; ++mi)
#pragma unroll
    for (int ni = 0; ni < 4; ++ni)
#pragma unroll
      for (int rr = 0; rr < 4; ++rr) {
        const int row = m0 + wr + mi * 16 + quad * 4 + rr;
        const int col = n0 + wc + ni * 16 + lrow;
        out[(size_t)row * HIDD + col] = __float2half(acc[mi][ni][rr]);
      }
}

__global__ __launch_bounds__(256) void k_rms2(const float* __restrict__ xb,
                                              const __half* __restrict__ Po,
                                              const float* __restrict__ w,
                                              float* __restrict__ hidden,
                                              unsigned short* __restrict__ h2b) {
  const int t = blockIdx.x;
  const int tid = threadIdx.x;
  float2 v[4];
  float ss = 0.f;
#pragma unroll
  for (int i = 0; i < 4; ++i) {
    const int c = (tid << 1) + (i << 9);
    const size_t idx = (size_t)t * HIDD + c;
    float2 a = *reinterpret_cast<const float2*>(xb + idx);
#pragma unroll
    for (int sp = 0; sp < 16; ++sp) {
      const float2 b = __half22float2(*reinterpret_cast<const __half2*>(Po + idx + (size_t)sp * (TT * HIDD)));
      a.x += b.x; a.y += b.y;
    }
    v[i] = a;
    ss += a.x * a.x + a.y * a.y;
  }
  __shared__ float red[4];
  const int lane = tid & 63, wid = tid >> 6;
#pragma unroll
  for (int o = 32; o; o >>= 1) ss += __shfl_xor(ss, o);
  if (!lane) red[wid] = ss;
  __syncthreads();
  const float tot = red[0] + red[1] + red[2] + red[3];
  const float r = rsqrtf(tot * (1.0f / HIDD) + 1e-6f);
#pragma unroll
  for (int i = 0; i < 4; ++i) {
    const int c = (tid << 1) + (i << 9);
    const size_t idx = (size_t)t * HIDD + c;
    *reinterpret_cast<float2*>(hidden + idx) = v[i];
    const float2 wv2 = *reinterpret_cast<const float2*>(w + c);
    *reinterpret_cast<unsigned int*>(h2b + idx) = f2b2(v[i].x * r * wv2.x, v[i].y * r * wv2.y);
  }
}

// gate_up GEMM: BM=128, split-K=2, fp16 partials. grid 768 = 4 mt x 96 nt x 2 s.
__global__ __launch_bounds__(256) void k_gemm_gu(const unsigned short* __restrict__ h2b,
                                                 const float* __restrict__ wgu,
                                                 __half* __restrict__ guh) {
  __shared__ __align__(16) unsigned char Ls[2 * (128 * 64 + 16384)];
  int mt, nt, s;
  swz<2>(blockIdx.x, mt, nt, s);  // NT=96, S=2 -> 768 blocks
  const int m0 = mt << 7, n0 = nt << 7;
  ZERO_ACC(4)
  gemm_core<128, false>(h2b + (size_t)m0 * HIDD, HIDD, wgu + (size_t)n0 * HIDD, HIDD,
                        s * 1024, s * 1024 + 1024, acc, Ls);
  EPI_VARS
  const int wr = (wave >> 1) << 6;
  __half* out = guh + (size_t)s * (TT * 2 * INTR);
#pragma unroll
  for (int mi = 0; mi < 4; ++mi)
#pragma unroll
    for (int ni = 0; ni < 4; ++ni)
#pragma unroll
      for (int rr = 0; rr < 4; ++rr) {
        const int row = m0 + wr + mi * 16 + quad * 4 + rr;
        const int col = n0 + wc + ni * 16 + lrow;
        out[(size_t)row * (2 * INTR) + col] = __float2half(acc[mi][ni][rr]);
      }
}

__global__ __launch_bounds__(256) void k_silu(const __half* __restrict__ guh,
                                              unsigned short* __restrict__ actb) {
  const int j0 = (blockIdx.x * 256 + threadIdx.x) << 1;  // grid.x = 12
  const int t = blockIdx.y;
  const size_t base = (size_t)t * (2 * INTR) + j0;
  const size_t off = (size_t)TT * (2 * INTR);
  const float2 g0 = __half22float2(*reinterpret_cast<const __half2*>(guh + base));
  const float2 g1 = __half22float2(*reinterpret_cast<const __half2*>(guh + off + base));
  const float2 u0 = __half22float2(*reinterpret_cast<const __half2*>(guh + base + INTR));
  const float2 u1 = __half22float2(*reinterpret_cast<const __half2*>(guh + off + base + INTR));
  const float gx = g0.x + g1.x, gy = g0.y + g1.y;
  const float ux = u0.x + u1.x, uy = u0.y + u1.y;
  const float a0 = gx / (1.f + __expf(-gx)) * ux;
  const float a1 = gy / (1.f + __expf(-gy)) * uy;
  *reinterpret_cast<unsigned int*>(actb + (size_t)t * INTR + j0) = f2b2(a0, a1);
}

__global__ __launch_bounds__(256) void k_gemm_down(const unsigned short* __restrict__ actb,
                                                   const float* __restrict__ wdn,
                                                   __half* __restrict__ Pdn) {
  __shared__ __align__(16) unsigned char Ls[2 * (128 * 64 + 16384)];
  int mt, nt, s;
  swz<12>(blockIdx.x, mt, nt, s);  // NT=16, S=12 -> 768 blocks, K=512 each
  const int m0 = mt << 7, n0 = nt << 7;
  ZERO_ACC(4)
  gemm_core<128, false>(actb + (size_t)m0 * INTR, INTR, wdn + (size_t)n0 * INTR, INTR,
                        s * 512, s * 512 + 512, acc, Ls);
  EPI_VARS
  const int wr = (wave >> 1) << 6;
  __half* out = Pdn + (size_t)s * (TT * HIDD);
#pragma unroll
  for (int mi = 0; mi < 4; ++mi)
#pragma unroll
    for (int ni = 0; ni < 4; ++ni)
#pragma unroll
      for (int rr = 0; rr < 4; ++rr) {
        const int row = m0 + wr + mi * 16 + quad * 4 + rr;
        const int col = n0 + wc + ni * 16 + lrow;
        out[(size_t)row * HIDD + col] = __float2half(acc[mi][ni][rr]);
      }
}

__global__ __launch_bounds__(256) void k_final(const float* __restrict__ hidden,
                                               const __half* __restrict__ Pdn,
                                               float* __restrict__ out0) {
  __shared__ float tile[32][33];
  const int c0 = blockIdx.x << 5, t0 = blockIdx.y << 5;
  const int tx = threadIdx.x & 31, ty0 = (threadIdx.x >> 5) << 2;
#pragma unroll
  for (int i = 0; i < 4; ++i) {
    const int t = t0 + ty0 + i;
    const size_t idx = (size_t)t * HIDD + c0 + tx;
    float a = hidden[idx];
#pragma unroll
    for (int sp = 0; sp < 12; ++sp) a += __half2float(Pdn[idx + (size_t)sp * (TT * HIDD)]);
    tile[ty0 + i][tx] = a;
  }
  __syncthreads();
#pragma unroll
  for (int i = 0; i < 4; ++i)
    out0[(size_t)(c0 + ty0 + i) * TT + t0 + tx] = tile[tx][ty0 + i];
}

extern "C" void kernel_launch(void* const* d_in, const int* in_sizes, int n_in,
                              void* d_out, int out_size, void* d_ws, size_t ws_size,
                              hipStream_t stream) {
  const float* conv   = (const float*)d_in[0];
  const float* cosb   = (const float*)d_in[1];
  const float* sinb   = (const float*)d_in[2];
  const float* kcache = (const float*)d_in[5];
  const float* vcache = (const float*)d_in[6];
  const float* wq  = (const float*)d_in[7];
  const float* wk  = (const float*)d_in[8];
  const float* wv  = (const float*)d_in[9];
  const float* wo  = (const float*)d_in[10];
  const float* ln1 = (const float*)d_in[11];
  const float* ln2 = (const float*)d_in[12];
  const float* qnw = (const float*)d_in[13];
  const float* knw = (const float*)d_in[14];
  const float* wgu = (const float*)d_in[15];
  const float* wdn = (const float*)d_in[16];

  float* ws = (float*)d_ws;
  // layout (floats): total 14,155,776 f = 56.6 MB (< 71.3 MB proven in R1/R2)
  float* xb = ws + 0;                                      // 1,048,576
  unsigned short* h1b  = (unsigned short*)(ws + 1048576);  // 524,288 f ; later o_inb
  unsigned short* o_inb = h1b;
  unsigned short* h2b  = (unsigned short*)(ws + 1572864);  // 524,288 f
  float* hidden = ws + 2097152;                            // 1,048,576
  unsigned short* qb  = (unsigned short*)(ws + 3145728);   // 16*512*128 us
  unsigned short* kb  = qb + 1048576;                      // 8*512*128 us
  unsigned short* vtb = kb + 524288;                       // 8*128*512 us (d-major)
  unsigned short* actb = (unsigned short*)(ws + 4194304);  // 512*6144 us = 1,572,864 f
  float* R   = ws + 5767168;                               // 8,388,608 f shared region:
  __half* Pqh = (__half*)R;                                //  qkv:  4 x 2,097,152 halves = 4.2M f
  unsigned short* Pb = (unsigned short*)R;                 //  attn: 2,097,152 f-slots
  float* sc  = R + 2097152;                                //  attn: 4,194,304
  float* Ppv = R + 2097152;                                //  pv:   4 x 1,048,576 (over dead sc)
  __half* Poh = (__half*)R;                                //  o:    16 x 1,048,576 halves = 8.4M f (whole R)
  __half* guh = (__half*)R;                                //  mlp:  2 x 6,291,456 halves
  __half* Pdnh = (__half*)R;                               //  down: 12 x 1,048,576 halves = 6.3M f

  float* out0 = (float*)d_out;   // (HID, T)
  float* kout = out0 + 1048576;  // (NKV, SEQ, D)
  float* vout = kout + 4194304;  // (NKV, SEQ, D)

  k_rms1<<<16, 1024, 0, stream>>>(conv, ln1, xb, h1b);
  k_gemm_qkv<<<512, 256, 0, stream>>>(h1b, wq, wk, wv, Pqh);
  k_rope<<<dim3(NH + 2 * NKV, TT), 128, 0, stream>>>(Pqh, cosb, sinb, qnw, knw, qb, kb, vtb, kout, vout);
  k_tail<<<4096, 256, 0, stream>>>(kcache, vcache, kout, vout);
  k_scores<<<dim3(8, 4, NH), 256, 0, stream>>>(qb, kb, sc);
  k_softmax<<<NH * TT, 256, 0, stream>>>(sc, Pb);
  k_pv<<<dim3(8, NH, 4), 256, 0, stream>>>(Pb, vtb, Ppv);
  k_red_pv<<<1024, 256, 0, stream>>>(Ppv, o_inb);
  k_gemm_o<<<1024, 256, 0, stream>>>(o_inb, wo, Poh);
  k_rms2<<<TT, 256, 0, stream>>>(xb, Poh, ln2, hidden, h2b);
  k_gemm_gu<<<768, 256, 0, stream>>>(h2b, wgu, guh);
  k_silu<<<dim3(12, TT), 256, 0, stream>>>(guh, actb);
  k_gemm_down<<<768, 256, 0, stream>>>(actb, wdn, Pdnh);
  k_final<<<dim3(HIDD / 32, TT / 32), 256, 0, stream>>>(hidden, Pdnh, out0);
}

// Round 6
// 459.035 us; speedup vs baseline: 1.0596x; 1.0254x over previous
//
#include <hip/hip_runtime.h>
#include <hip/hip_bf16.h>
#include <hip/hip_fp16.h>

#define TT 512
#define HIDD 2048
#define NH 16
#define NKV 8
#define DD 128
#define INTR 6144
#define SEQ 4096
#define SCALE 0.08838834764831845f

typedef __attribute__((ext_vector_type(8))) short short8;
typedef __attribute__((ext_vector_type(4))) float floatx4;

static __device__ __forceinline__ unsigned short f2b(float f) {
  unsigned int u = __float_as_uint(f);
  u += 0x7fffu + ((u >> 16) & 1u);
  return (unsigned short)(u >> 16);
}

static __device__ __forceinline__ unsigned int f2b2(float a, float b) {
  __hip_bfloat162 h = __float22bfloat162_rn(make_float2(a, b));
  return *reinterpret_cast<unsigned int*>(&h);
}

// ---------------- GEMM core (R3-best structure, swizzle reverted) ----------------
// C(BMx128) += A(BMx[kbeg:kend]) * B(128x[kbeg:kend])^T
// A bf16 staged [BM][32] linear (64B rows). fp32-B staged [128][32] with
// slot^(row&7) swizzle (source+read). Pipeline: 2 LDS buffers, 2-deep DMA,
// counted vmcnt, raw barriers. R5's A-swizzle REVERTED (measured: conflicts are
// hidden under DMA latency; permuted source hurt coalescing, -6% on gu).

static __device__ __forceinline__ void gld16(const void* g, void* l) {
  __builtin_amdgcn_global_load_lds(
      (const __attribute__((address_space(1))) unsigned int*)g,
      (__attribute__((address_space(3))) unsigned int*)l, 16, 0, 0);
}

template <int BM, bool B16>
static __device__ __forceinline__ void stage_tile(const unsigned short* __restrict__ A, int lda,
                                                  const void* __restrict__ B, int ldb, int k0,
                                                  unsigned char* buf, int wave, int lane) {
  {  // A tile: BM x 32 bf16, 64B rows. 1KB per (wave,issue) = 16 rows.
    const int rpw = BM >> 2;
    const int rl = lane >> 2;
    const int c8 = (lane & 3) << 3;
#pragma unroll
    for (int i = 0; i < BM / 64; ++i) {
      const int rbase = wave * rpw + i * 16;
      gld16(A + (size_t)(rbase + rl) * lda + k0 + c8, buf + (size_t)rbase * 64);
    }
  }
  unsigned char* Bb = buf + BM * 64;
  if constexpr (B16) {  // B tile: 128 x 32 bf16, like A
    const unsigned short* Bh = (const unsigned short*)B;
    const int rl = lane >> 2;
    const int c8 = (lane & 3) << 3;
#pragma unroll
    for (int i = 0; i < 2; ++i) {
      const int rbase = wave * 32 + i * 16;
      gld16(Bh + (size_t)(rbase + rl) * ldb + k0 + c8, Bb + (size_t)rbase * 64);
    }
  } else {  // B tile: 128 x 32 f32, 128B rows; storage slot sp holds logical slot sp^(r&7)
    const float* Bf = (const float*)B;
    const int rl = lane >> 3;
    const int sp = lane & 7;
#pragma unroll
    for (int i = 0; i < 4; ++i) {
      const int rbase = wave * 32 + i * 8;
      const int r = rbase + rl;
      gld16(Bf + (size_t)r * ldb + k0 + ((sp ^ (r & 7)) << 2), Bb + (size_t)rbase * 128);
    }
  }
}

template <int BM, bool B16>
static __device__ __forceinline__ void frags_from(const unsigned char* buf, int wr, int wc,
                                                  int lrow, int koff,
                                                  short8 (&af)[BM / 32], short8 (&bfr)[4]) {
  const unsigned short* Ab = (const unsigned short*)buf;
#pragma unroll
  for (int mi = 0; mi < BM / 32; ++mi)
    af[mi] = *reinterpret_cast<const short8*>(Ab + (size_t)(wr + mi * 16 + lrow) * 32 + koff);
  if constexpr (B16) {
    const unsigned short* Bb = (const unsigned short*)(buf + BM * 64);
#pragma unroll
    for (int ni = 0; ni < 4; ++ni)
      bfr[ni] = *reinterpret_cast<const short8*>(Bb + (size_t)(wc + ni * 16 + lrow) * 32 + koff);
  } else {
    const float* Bf = (const float*)(buf + BM * 64);
    const int s0 = koff >> 2;  // koff in {0,8,16,24} -> 16B slot 0,2,4,6
#pragma unroll
    for (int ni = 0; ni < 4; ++ni) {
      const int r = wc + ni * 16 + lrow;
      const float4 x = *reinterpret_cast<const float4*>(Bf + (size_t)r * 32 + ((s0 ^ (r & 7)) << 2));
      const float4 y = *reinterpret_cast<const float4*>(Bf + (size_t)r * 32 + (((s0 + 1) ^ (r & 7)) << 2));
      union { short8 s; unsigned int u[4]; } pk;
      pk.u[0] = f2b2(x.x, x.y); pk.u[1] = f2b2(x.z, x.w);
      pk.u[2] = f2b2(y.x, y.y); pk.u[3] = f2b2(y.z, y.w);
      bfr[ni] = pk.s;
    }
  }
}

template <int BM, bool B16>
static __device__ __forceinline__ void gemm_core(const unsigned short* __restrict__ A, int lda,
                                                 const void* __restrict__ B, int ldb,
                                                 int kbeg, int kend, floatx4 (&acc)[BM / 32][4],
                                                 unsigned char* Ls) {
  constexpr int MI = BM / 32;
  constexpr int TILE = BM * 64 + (B16 ? 8192 : 16384);
  constexpr int NB = (BM / 64) + (B16 ? 2 : 4);  // DMA insts per wave per tile
  const int tid = threadIdx.x;
  const int lane = tid & 63, wave = tid >> 6;
  const int wr = (wave >> 1) * (BM >> 1);
  const int wc = (wave & 1) << 6;
  const int lrow = lane & 15;
  const int koff = (lane >> 4) << 3;
  const int NT = (kend - kbeg) >> 5;  // all callers: NT >= 4
  stage_tile<BM, B16>(A, lda, B, ldb, kbeg,      Ls,        wave, lane);
  stage_tile<BM, B16>(A, lda, B, ldb, kbeg + 32, Ls + TILE, wave, lane);
  int p = 0;
  for (int t = 0; t < NT - 1; ++t) {
    // wait tile t landed (tile t+1's NB loads stay in flight)
    if constexpr (NB == 6)      asm volatile("s_waitcnt vmcnt(6)" ::: "memory");
    else if constexpr (NB == 3) asm volatile("s_waitcnt vmcnt(3)" ::: "memory");
    else if constexpr (NB == 4) asm volatile("s_waitcnt vmcnt(4)" ::: "memory");
    else                        asm volatile("s_waitcnt vmcnt(5)" ::: "memory");
    __builtin_amdgcn_sched_barrier(0);
    __builtin_amdgcn_s_barrier();
    short8 af[MI], bfr[4];
    frags_from<BM, B16>(Ls + p * TILE, wr, wc, lrow, koff, af, bfr);
    asm volatile("s_waitcnt lgkmcnt(0)" ::: "memory");
    __builtin_amdgcn_sched_barrier(0);
    __builtin_amdgcn_s_barrier();  // all waves' reads of buf p retired -> safe to re-DMA
    if (t + 2 < NT)
      stage_tile<BM, B16>(A, lda, B, ldb, kbeg + (t + 2) * 32, Ls + p * TILE, wave, lane);
#pragma unroll
    for (int mi = 0; mi < MI; ++mi)
#pragma unroll
      for (int ni = 0; ni < 4; ++ni)
        acc[mi][ni] = __builtin_amdgcn_mfma_f32_16x16x32_bf16(af[mi], bfr[ni], acc[mi][ni], 0, 0, 0);
    p ^= 1;
  }
  asm volatile("s_waitcnt vmcnt(0)" ::: "memory");
  __builtin_amdgcn_sched_barrier(0);
  __builtin_amdgcn_s_barrier();
  {
    short8 af[MI], bfr[4];
    frags_from<BM, B16>(Ls + p * TILE, wr, wc, lrow, koff, af, bfr);
#pragma unroll
    for (int mi = 0; mi < MI; ++mi)
#pragma unroll
      for (int ni = 0; ni < 4; ++ni)
        acc[mi][ni] = __builtin_amdgcn_mfma_f32_16x16x32_bf16(af[mi], bfr[ni], acc[mi][ni], 0, 0, 0);
  }
}

#define EPI_VARS \
  const int lane = threadIdx.x & 63; \
  const int wave = threadIdx.x >> 6; \
  const int wc = (wave & 1) << 6;    \
  const int lrow = lane & 15;        \
  const int quad = lane >> 4;

#define ZERO_ACC(MI_) \
  floatx4 acc[MI_][4]; \
  _Pragma("unroll") for (int mi = 0; mi < MI_; ++mi) \
  _Pragma("unroll") for (int ni = 0; ni < 4; ++ni) { floatx4 z = {0.f, 0.f, 0.f, 0.f}; acc[mi][ni] = z; }

// XCD swizzle: 4 mt-blocks of one (nt,split) group at b, b+8, b+16, b+24 -> same bid%8 -> same XCD
template <int S>
static __device__ __forceinline__ void swz(int b, int& mt, int& nt, int& s) {
  mt = (b >> 3) & 3;
  const int gid = ((b >> 5) << 3) | (b & 7);
  nt = gid / S;
  s = gid - nt * S;
}

// ---------------- kernels ----------------

__global__ __launch_bounds__(1024) void k_rms1(const float* __restrict__ conv,
                                               const float* __restrict__ w,
                                               float* __restrict__ xb,
                                               unsigned short* __restrict__ h1b) {
  const int t0 = blockIdx.x << 5;  // 16 blocks x 32 t
  const int tid = threadIdx.x;
  const int j = tid & 31;   // t-lane (phase1) / c-lane (phase2 out)
  const int g = tid >> 5;   // c-row 0..31
  __shared__ float part[32][32];
  __shared__ float tile[32][33];
  __shared__ float rs[32];
  float ss = 0.f;
  for (int c0 = 0; c0 < HIDD; c0 += 32) {
    const float v = conv[(size_t)(c0 + g) * TT + t0 + j];
    ss += v * v;
  }
  part[g][j] = ss;
  __syncthreads();
  if (g == 0) {
    float tot = 0.f;
#pragma unroll
    for (int q = 0; q < 32; ++q) tot += part[q][j];
    rs[j] = rsqrtf(tot * (1.0f / HIDD) + 1e-6f);
  }
  __syncthreads();
  for (int c0 = 0; c0 < HIDD; c0 += 32) {
    tile[g][j] = conv[(size_t)(c0 + g) * TT + t0 + j];
    __syncthreads();
    const float v = tile[j][g];  // j = c index, g = t index
    const float rv = rs[g];
    xb[(size_t)(t0 + g) * HIDD + c0 + j] = v;
    h1b[(size_t)(t0 + g) * HIDD + c0 + j] = f2b(v * rv * w[c0 + j]);
    __syncthreads();
  }
}

__global__ __launch_bounds__(256) void k_gemm_qkv(const unsigned short* __restrict__ h1b,
                                                  const float* __restrict__ wq,
                                                  const float* __restrict__ wk,
                                                  const float* __restrict__ wv,
                                                  __half* __restrict__ Pq) {
  __shared__ __align__(16) unsigned char Ls[2 * (128 * 64 + 16384)];
  int mt, nt, s;
  swz<4>(blockIdx.x, mt, nt, s);  // NT=32, S=4 -> 512 blocks
  const int m0 = mt << 7, n0 = nt << 7;
  const float* Bp;
  if (n0 < 2048)      Bp = wq + (size_t)n0 * HIDD;
  else if (n0 < 3072) Bp = wk + (size_t)(n0 - 2048) * HIDD;
  else                Bp = wv + (size_t)(n0 - 3072) * HIDD;
  ZERO_ACC(4)
  gemm_core<128, false>(h1b + (size_t)m0 * HIDD, HIDD, Bp, HIDD, s * 512, s * 512 + 512, acc, Ls);
  EPI_VARS
  const int wr = (wave >> 1) << 6;
  __half* out = Pq + (size_t)s * (TT * 4096);
#pragma unroll
  for (int mi = 0; mi < 4; ++mi)
#pragma unroll
    for (int ni = 0; ni < 4; ++ni)
#pragma unroll
      for (int rr = 0; rr < 4; ++rr) {
        const int row = m0 + wr + mi * 16 + quad * 4 + rr;
        const int col = n0 + wc + ni * 16 + lrow;
        out[(size_t)row * 4096 + col] = __float2half(acc[mi][ni][rr]);
      }
}

__global__ __launch_bounds__(128) void k_rope(const __half* __restrict__ Pq,
                                              const float* __restrict__ cosb,
                                              const float* __restrict__ sinb,
                                              const float* __restrict__ qnw,
                                              const float* __restrict__ knw,
                                              unsigned short* __restrict__ qb,
                                              unsigned short* __restrict__ kb,
                                              unsigned short* __restrict__ vtb,
                                              float* __restrict__ kout,
                                              float* __restrict__ vout) {
  const int u = blockIdx.x;  // 0..15 q, 16..23 k, 24..31 v
  const int t = blockIdx.y;
  const int d = threadIdx.x;
  __shared__ float red[2];
  __shared__ float sh[DD];
  int slot;
  if (u < NH)            slot = u * DD + d;
  else if (u < NH + NKV) slot = 2048 + (u - NH) * DD + d;
  else                   slot = 3072 + (u - NH - NKV) * DD + d;
  const size_t idx = (size_t)t * 4096 + slot;
  float val = __half2float(Pq[idx]) + __half2float(Pq[idx + (size_t)TT * 4096]) +
              __half2float(Pq[idx + 2 * (size_t)TT * 4096]) + __half2float(Pq[idx + 3 * (size_t)TT * 4096]);
  if (u < NH + NKV) {
    float ss = val * val;
    const int lane = d & 63, wid = d >> 6;
#pragma unroll
    for (int o = 32; o; o >>= 1) ss += __shfl_xor(ss, o);
    if (!lane) red[wid] = ss;
    __syncthreads();
    const float r = rsqrtf((red[0] + red[1]) * (1.0f / DD) + 1e-6f);
    const float w = (u < NH) ? qnw[d] : knw[d];
    const float nv = val * r * w;
    sh[d] = nv;
    __syncthreads();
    const float partner = sh[d ^ 64];
    const float rh = (d < 64) ? -partner : partner;
    const float o = nv * cosb[(size_t)t * DD + d] + rh * sinb[(size_t)t * DD + d];
    if (u < NH) {
      qb[(size_t)u * TT * DD + (size_t)t * DD + d] = f2b(o);
    } else {
      const int kh = u - NH;
      kout[(size_t)kh * SEQ * DD + (size_t)t * DD + d] = o;
      kb[(size_t)kh * TT * DD + (size_t)t * DD + d] = f2b(o);
    }
  } else {
    const int vh = u - NH - NKV;
    vout[(size_t)vh * SEQ * DD + (size_t)t * DD + d] = val;
    vtb[(size_t)vh * DD * TT + (size_t)d * TT + t] = f2b(val);
  }
}

// scores with causal tile skip: fully-masked tiles (n0 >= m0+64) are neither
// computed nor written; k_softmax guards those columns explicitly.
__global__ __launch_bounds__(256) void k_scores(const unsigned short* __restrict__ qb,
                                                const unsigned short* __restrict__ kb,
                                                float* __restrict__ sc) {
  const int m0 = blockIdx.x << 6, n0 = blockIdx.y << 7, h = blockIdx.z;
  if (n0 >= m0 + 64) return;  // entire tile masked
  __shared__ __align__(16) unsigned char Ls[2 * (64 * 64 + 8192)];
  ZERO_ACC(2)
  gemm_core<64, true>(qb + (size_t)h * TT * DD + (size_t)m0 * DD, DD,
                      kb + (size_t)(h >> 1) * TT * DD + (size_t)n0 * DD, DD, 0, DD, acc, Ls);
  EPI_VARS
  const int wr = (wave >> 1) << 5;
  float* out = sc + (size_t)h * TT * TT;
#pragma unroll
  for (int mi = 0; mi < 2; ++mi)
#pragma unroll
    for (int ni = 0; ni < 4; ++ni)
#pragma unroll
      for (int rr = 0; rr < 4; ++rr) {
        const int t = m0 + wr + mi * 16 + quad * 4 + rr;
        const int s = n0 + wc + ni * 16 + lrow;
        float v = acc[mi][ni][rr] * SCALE;
        if (s > t) v += -10000.0f;
        out[(size_t)t * TT + s] = v;
      }
}

// softmax (first NH*TT blocks) + fused KV-cache tail copy (last 4096 blocks).
__global__ __launch_bounds__(256) void k_softmax(const float* __restrict__ sc,
                                                 unsigned short* __restrict__ Pb,
                                                 const float* __restrict__ kc,
                                                 const float* __restrict__ vc,
                                                 float* __restrict__ ko,
                                                 float* __restrict__ vo) {
  const int bid = blockIdx.x;
  const int tid = threadIdx.x;
  if (bid >= NH * TT) {  // tail copy: rows s >= TT of the 8-head KV caches
    const int i = (bid - NH * TT) * 256 + tid;  // float4 index
    const int e = i << 2;
    const int s = (e >> 7) & (SEQ - 1);
    if (s >= TT) {
      reinterpret_cast<float4*>(ko)[i] = reinterpret_cast<const float4*>(kc)[i];
      reinterpret_cast<float4*>(vo)[i] = reinterpret_cast<const float4*>(vc)[i];
    }
    return;
  }
  const int h = bid >> 9, t = bid & 511;
  const float* row = sc + ((size_t)h * TT + t) * TT;
  float v0 = (tid <= t) ? row[tid] : -1e30f;
  float v1 = (tid + 256 <= t) ? row[tid + 256] : -1e30f;
  __shared__ float red[4];
  const int lane = tid & 63, wid = tid >> 6;
  float m = fmaxf(v0, v1);
#pragma unroll
  for (int o = 32; o; o >>= 1) m = fmaxf(m, __shfl_xor(m, o));
  if (!lane) red[wid] = m;
  __syncthreads();
  m = fmaxf(fmaxf(red[0], red[1]), fmaxf(red[2], red[3]));
  const float e0 = __expf(v0 - m), e1 = __expf(v1 - m);
  float s = e0 + e1;
  __syncthreads();
#pragma unroll
  for (int o = 32; o; o >>= 1) s += __shfl_xor(s, o);
  if (!lane) red[wid] = s;
  __syncthreads();
  const float inv = 1.0f / (red[0] + red[1] + red[2] + red[3]);
  unsigned short* orow = Pb + ((size_t)h * TT + t) * TT;
  orow[tid] = f2b(e0 * inv);
  orow[tid + 256] = f2b(e1 * inv);
}

// pv with causal chunk skip: s-chunks entirely above the diagonal contribute
// zeros; acc stays zero-init and the epilogue writes zeros (red_pv sums all 4).
__global__ __launch_bounds__(256) void k_pv(const unsigned short* __restrict__ Pb,
                                            const unsigned short* __restrict__ vtb,
                                            float* __restrict__ Ppv) {
  __shared__ __align__(16) unsigned char Ls[2 * (64 * 64 + 8192)];
  const int m0 = blockIdx.x << 6, h = blockIdx.y, s = blockIdx.z;
  ZERO_ACC(2)
  if (s * 128 <= m0 + 63)
    gemm_core<64, true>(Pb + (size_t)h * TT * TT + (size_t)m0 * TT, TT,
                        vtb + (size_t)(h >> 1) * DD * TT, TT, s * 128, s * 128 + 128, acc, Ls);
  EPI_VARS
  const int wr = (wave >> 1) << 5;
  float* out = Ppv + (size_t)s * (TT * HIDD);
#pragma unroll
  for (int mi = 0; mi < 2; ++mi)
#pragma unroll
    for (int ni = 0; ni < 4; ++ni)
#pragma unroll
      for (int rr = 0; rr < 4; ++rr) {
        const int row = m0 + wr + mi * 16 + quad * 4 + rr;
        const int col = wc + ni * 16 + lrow;
        out[(size_t)row * HIDD + h * DD + col] = acc[mi][ni][rr];
      }
}

__global__ __launch_bounds__(256) void k_red_pv(const float* __restrict__ Ppv,
                                                unsigned short* __restrict__ o_inb) {
  const int i = blockIdx.x * 256 + threadIdx.x;  // float4 index over 512*2048/4
  const float4* p = reinterpret_cast<const float4*>(Ppv);
  float4 a = p[i];
  const float4 b = p[i + 262144], c = p[i + 524288], d = p[i + 786432];
  a.x += b.x + c.x + d.x; a.y += b.y + c.y + d.y;
  a.z += b.z + c.z + d.z; a.w += b.w + c.w + d.w;
  uint2 o;
  o.x = f2b2(a.x, a.y);
  o.y = f2b2(a.z, a.w);
  *reinterpret_cast<uint2*>(o_inb + (size_t)i * 4) = o;
}

__global__ __launch_bounds__(256) void k_gemm_o(const unsigned short* __restrict__ o_inb,
                                                const float* __restrict__ wo,
                                                __half* __restrict__ Po) {
  __shared__ __align__(16) unsigned char Ls[2 * (128 * 64 + 16384)];
  int mt, nt, s;
  swz<8>(blockIdx.x, mt, nt, s);  // NT=16, S=8 -> 512 blocks, K=256 each
  const int m0 = mt << 7, n0 = nt << 7;
  ZERO_ACC(4)
  gemm_core<128, false>(o_inb + (size_t)m0 * HIDD, HIDD, wo + (size_t)n0 * HIDD, HIDD,
                        s * 256, s * 256 + 256, acc, Ls);
  EPI_VARS
  const int wr = (wave >> 1) << 6;
  __half* out = Po + (size_t)s * (TT * HIDD);
#pragma unroll
  for (int mi = 0; mi < 4; ++mi)
#pragma unroll
    for (int ni = 0; ni < 4; ++ni)
#pragma unroll
      for (int rr = 0; rr < 4; ++rr) {
        const int row = m0 + wr + mi * 16 + quad * 4 + rr;
        const int col = n0 + wc + ni * 16 + lrow;
        out[(size_t)row * HIDD + col] = __float2half(acc[mi][ni][rr]);
      }
}

__global__ __launch_bounds__(256) void k_rms2(const float* __restrict__ xb,
                                              const __half* __restrict__ Po,
                                              const float* __restrict__ w,
                                              float* __restrict__ hidden,
                                              unsigned short* __restrict__ h2b) {
  const int t = blockIdx.x;
  const int tid = threadIdx.x;
  float2 v[4];
  float ss = 0.f;
#pragma unroll
  for (int i = 0; i < 4; ++i) {
    const int c = (tid << 1) + (i << 9);
    const size_t idx = (size_t)t * HIDD + c;
    float2 a = *reinterpret_cast<const float2*>(xb + idx);
#pragma unroll
    for (int sp = 0; sp < 8; ++sp) {
      const float2 b = __half22float2(*reinterpret_cast<const __half2*>(Po + idx + (size_t)sp * (TT * HIDD)));
      a.x += b.x; a.y += b.y;
    }
    v[i] = a;
    ss += a.x * a.x + a.y * a.y;
  }
  __shared__ float red[4];
  const int lane = tid & 63, wid = tid >> 6;
#pragma unroll
  for (int o = 32; o; o >>= 1) ss += __shfl_xor(ss, o);
  if (!lane) red[wid] = ss;
  __syncthreads();
  const float tot = red[0] + red[1] + red[2] + red[3];
  const float r = rsqrtf(tot * (1.0f / HIDD) + 1e-6f);
#pragma unroll
  for (int i = 0; i < 4; ++i) {
    const int c = (tid << 1) + (i << 9);
    const size_t idx = (size_t)t * HIDD + c;
    *reinterpret_cast<float2*>(hidden + idx) = v[i];
    const float2 wv2 = *reinterpret_cast<const float2*>(w + c);
    *reinterpret_cast<unsigned int*>(h2b + idx) = f2b2(v[i].x * r * wv2.x, v[i].y * r * wv2.y);
  }
}

// gate_up GEMM: BM=128, split-K=2, fp16 partials. grid 768 = 4 mt x 96 nt x 2 s.
__global__ __launch_bounds__(256) void k_gemm_gu(const unsigned short* __restrict__ h2b,
                                                 const float* __restrict__ wgu,
                                                 __half* __restrict__ guh) {
  __shared__ __align__(16) unsigned char Ls[2 * (128 * 64 + 16384)];
  int mt, nt, s;
  swz<2>(blockIdx.x, mt, nt, s);  // NT=96, S=2 -> 768 blocks
  const int m0 = mt << 7, n0 = nt << 7;
  ZERO_ACC(4)
  gemm_core<128, false>(h2b + (size_t)m0 * HIDD, HIDD, wgu + (size_t)n0 * HIDD, HIDD,
                        s * 1024, s * 1024 + 1024, acc, Ls);
  EPI_VARS
  const int wr = (wave >> 1) << 6;
  __half* out = guh + (size_t)s * (TT * 2 * INTR);
#pragma unroll
  for (int mi = 0; mi < 4; ++mi)
#pragma unroll
    for (int ni = 0; ni < 4; ++ni)
#pragma unroll
      for (int rr = 0; rr < 4; ++rr) {
        const int row = m0 + wr + mi * 16 + quad * 4 + rr;
        const int col = n0 + wc + ni * 16 + lrow;
        out[(size_t)row * (2 * INTR) + col] = __float2half(acc[mi][ni][rr]);
      }
}

__global__ __launch_bounds__(256) void k_silu(const __half* __restrict__ guh,
                                              unsigned short* __restrict__ actb) {
  const int j0 = (blockIdx.x * 256 + threadIdx.x) << 1;  // grid.x = 12
  const int t = blockIdx.y;
  const size_t base = (size_t)t * (2 * INTR) + j0;
  const size_t off = (size_t)TT * (2 * INTR);
  const float2 g0 = __half22float2(*reinterpret_cast<const __half2*>(guh + base));
  const float2 g1 = __half22float2(*reinterpret_cast<const __half2*>(guh + off + base));
  const float2 u0 = __half22float2(*reinterpret_cast<const __half2*>(guh + base + INTR));
  const float2 u1 = __half22float2(*reinterpret_cast<const __half2*>(guh + off + base + INTR));
  const float gx = g0.x + g1.x, gy = g0.y + g1.y;
  const float ux = u0.x + u1.x, uy = u0.y + u1.y;
  const float a0 = gx / (1.f + __expf(-gx)) * ux;
  const float a1 = gy / (1.f + __expf(-gy)) * uy;
  *reinterpret_cast<unsigned int*>(actb + (size_t)t * INTR + j0) = f2b2(a0, a1);
}

__global__ __launch_bounds__(256) void k_gemm_down(const unsigned short* __restrict__ actb,
                                                   const float* __restrict__ wdn,
                                                   __half* __restrict__ Pdn) {
  __shared__ __align__(16) unsigned char Ls[2 * (128 * 64 + 16384)];
  int mt, nt, s;
  swz<12>(blockIdx.x, mt, nt, s);  // NT=16, S=12 -> 768 blocks, K=512 each
  const int m0 = mt << 7, n0 = nt << 7;
  ZERO_ACC(4)
  gemm_core<128, false>(actb + (size_t)m0 * INTR, INTR, wdn + (size_t)n0 * INTR, INTR,
                        s * 512, s * 512 + 512, acc, Ls);
  EPI_VARS
  const int wr = (wave >> 1) << 6;
  __half* out = Pdn + (size_t)s * (TT * HIDD);
#pragma unroll
  for (int mi = 0; mi < 4; ++mi)
#pragma unroll
    for (int ni = 0; ni < 4; ++ni)
#pragma unroll
      for (int rr = 0; rr < 4; ++rr) {
        const int row = m0 + wr + mi * 16 + quad * 4 + rr;
        const int col = n0 + wc + ni * 16 + lrow;
        out[(size_t)row * HIDD + col] = __float2half(acc[mi][ni][rr]);
      }
}

__global__ __launch_bounds__(256) void k_final(const float* __restrict__ hidden,
                                               const __half* __restrict__ Pdn,
                                               float* __restrict__ out0) {
  __shared__ float tile[32][33];
  const int c0 = blockIdx.x << 5, t0 = blockIdx.y << 5;
  const int tx = threadIdx.x & 31, ty0 = (threadIdx.x >> 5) << 2;
#pragma unroll
  for (int i = 0; i < 4; ++i) {
    const int t = t0 + ty0 + i;
    const size_t idx = (size_t)t * HIDD + c0 + tx;
    float a = hidden[idx];
#pragma unroll
    for (int sp = 0; sp < 12; ++sp) a += __half2float(Pdn[idx + (size_t)sp * (TT * HIDD)]);
    tile[ty0 + i][tx] = a;
  }
  __syncthreads();
#pragma unroll
  for (int i = 0; i < 4; ++i)
    out0[(size_t)(c0 + ty0 + i) * TT + t0 + tx] = tile[tx][ty0 + i];
}

extern "C" void kernel_launch(void* const* d_in, const int* in_sizes, int n_in,
                              void* d_out, int out_size, void* d_ws, size_t ws_size,
                              hipStream_t stream) {
  const float* conv   = (const float*)d_in[0];
  const float* cosb   = (const float*)d_in[1];
  const float* sinb   = (const float*)d_in[2];
  const float* kcache = (const float*)d_in[5];
  const float* vcache = (const float*)d_in[6];
  const float* wq  = (const float*)d_in[7];
  const float* wk  = (const float*)d_in[8];
  const float* wv  = (const float*)d_in[9];
  const float* wo  = (const float*)d_in[10];
  const float* ln1 = (const float*)d_in[11];
  const float* ln2 = (const float*)d_in[12];
  const float* qnw = (const float*)d_in[13];
  const float* knw = (const float*)d_in[14];
  const float* wgu = (const float*)d_in[15];
  const float* wdn = (const float*)d_in[16];

  float* ws = (float*)d_ws;
  float* xb = ws + 0;                                      // 1,048,576
  unsigned short* h1b  = (unsigned short*)(ws + 1048576);  // 524,288 f ; later o_inb
  unsigned short* o_inb = h1b;
  unsigned short* h2b  = (unsigned short*)(ws + 1572864);  // 524,288 f
  float* hidden = ws + 2097152;                            // 1,048,576
  unsigned short* qb  = (unsigned short*)(ws + 3145728);   // 16*512*128 us
  unsigned short* kb  = qb + 1048576;                      // 8*512*128 us
  unsigned short* vtb = kb + 524288;                       // 8*128*512 us (d-major)
  unsigned short* actb = (unsigned short*)(ws + 4194304);  // 512*6144 us = 1,572,864 f
  float* R   = ws + 5767168;                               // 8,388,608 f shared region:
  __half* Pqh = (__half*)R;                                //  qkv:  4 x 2,097,152 halves
  unsigned short* Pb = (unsigned short*)R;                 //  attn: 2,097,152 f-slots
  float* sc  = R + 2097152;                                //  attn: 4,194,304
  float* Ppv = R + 2097152;                                //  pv:   4 x 1,048,576 (over dead sc)
  __half* Poh = (__half*)R;                                //  o:    8 x 1,048,576 halves
  __half* guh = (__half*)R;                                //  mlp:  2 x 6,291,456 halves
  __half* Pdnh = (__half*)R;                               //  down: 12 x 1,048,576 halves

  float* out0 = (float*)d_out;   // (HID, T)
  float* kout = out0 + 1048576;  // (NKV, SEQ, D)
  float* vout = kout + 4194304;  // (NKV, SEQ, D)

  k_rms1<<<16, 1024, 0, stream>>>(conv, ln1, xb, h1b);
  k_gemm_qkv<<<512, 256, 0, stream>>>(h1b, wq, wk, wv, Pqh);
  k_rope<<<dim3(NH + 2 * NKV, TT), 128, 0, stream>>>(Pqh, cosb, sinb, qnw, knw, qb, kb, vtb, kout, vout);
  k_scores<<<dim3(8, 4, NH), 256, 0, stream>>>(qb, kb, sc);
  k_softmax<<<NH * TT + 4096, 256, 0, stream>>>(sc, Pb, kcache, vcache, kout, vout);
  k_pv<<<dim3(8, NH, 4), 256, 0, stream>>>(Pb, vtb, Ppv);
  k_red_pv<<<1024, 256, 0, stream>>>(Ppv, o_inb);
  k_gemm_o<<<512, 256, 0, stream>>>(o_inb, wo, Poh);
  k_rms2<<<TT, 256, 0, stream>>>(xb, Poh, ln2, hidden, h2b);
  k_gemm_gu<<<768, 256, 0, stream>>>(h2b, wgu, guh);
  k_silu<<<dim3(12, TT), 256, 0, stream>>>(guh, actb);
  k_gemm_down<<<768, 256, 0, stream>>>(actb, wdn, Pdnh);
  k_final<<<dim3(HIDD / 32, TT / 32), 256, 0, stream>>>(hidden, Pdnh, out0);
}